// Round 3
// baseline (2280.349 us; speedup 1.0000x reference)
//
#include <hip/hip_runtime.h>
#include <hip/hip_bf16.h>
#include <math.h>

#define SHIFT_ 4
#define NH_ 8
#define DIM_ 256
#define COND_ 128
#define HID_ 1024

typedef __hip_bfloat16 bf16;

__device__ inline float u2f_lo(unsigned u) { return __uint_as_float(u << 16); }
__device__ inline float u2f_hi(unsigned u) { return __uint_as_float(u & 0xFFFF0000u); }
__device__ inline unsigned pack2(float a, float b) {
  bf16 x = __float2bfloat16(a), y = __float2bfloat16(b);
  unsigned short ux = *(unsigned short*)&x, uy = *(unsigned short*)&y;
  return (unsigned)ux | ((unsigned)uy << 16);
}

// ---------------- mod = cond @ w + b  (both mod1 and mod2) ----------------
__global__ __launch_bounds__(256) void mod_kernel(const float* __restrict__ cond,
    const float* __restrict__ w1, const float* __restrict__ b1,
    const float* __restrict__ w2, const float* __restrict__ b2,
    float* __restrict__ mod1, float* __restrict__ mod2) {
  int gid = blockIdx.x * 256 + threadIdx.x;   // 0..16383
  int sel = gid >> 13;
  int r   = gid & 8191;
  int b   = r >> 9;
  int c   = r & 511;
  const float* w  = sel ? w2 : w1;
  const float* bb = sel ? b2 : b1;
  const float* cp = cond + b * COND_;
  float acc = bb[c];
#pragma unroll 4
  for (int k = 0; k < COND_; ++k) acc += cp[k] * w[k * 512 + c];
  (sel ? mod2 : mod1)[b * 512 + c] = acc;
}

// ---------------- adaLN -> bf16 out (+ optional shift-window gather) ----------------
// MODE 0: dst rows in window-token order; src gathered via roll(-4,-4).
// MODE 1: identity rows.
template <int MODE>
__global__ __launch_bounds__(256) void adaln_kernel(const float* __restrict__ x,
    const float* __restrict__ mod, const float* __restrict__ gamma,
    const float* __restrict__ beta, bf16* __restrict__ out) {
  int lane = threadIdx.x & 63;
  int row  = blockIdx.x * 4 + (threadIdx.x >> 6);   // 0..65535
  int b, src;
  if (MODE == 0) {
    int w = row >> 6, n = row & 63;
    b = w >> 6;
    int wi = (w >> 3) & 7, wj = w & 7;
    int rr = (wi * 8 + (n >> 3) + SHIFT_) & 63;
    int cc = (wj * 8 + (n & 7) + SHIFT_) & 63;
    src = rr * 64 + cc;
  } else {
    b   = row >> 12;
    src = row & 4095;
  }
  float4 v = ((const float4*)(x + ((long)b * 4096 + src) * DIM_))[lane];
  float s  = v.x + v.y + v.z + v.w;
  float sq = v.x * v.x + v.y * v.y + v.z * v.z + v.w * v.w;
#pragma unroll
  for (int off = 32; off >= 1; off >>= 1) {
    s  += __shfl_xor(s, off);
    sq += __shfl_xor(sq, off);
  }
  float mean = s * (1.f / DIM_);
  float var  = sq * (1.f / DIM_) - mean * mean;
  float rstd = rsqrtf(var + 1e-6f);
  float4 g  = ((const float4*)gamma)[lane];
  float4 bt = ((const float4*)beta)[lane];
  float4 dg = ((const float4*)(mod + b * 512))[lane];
  float4 db = ((const float4*)(mod + b * 512 + 256))[lane];
  float ox = g.x * (1.f + dg.x) * ((v.x - mean) * rstd) + bt.x + db.x;
  float oy = g.y * (1.f + dg.y) * ((v.y - mean) * rstd) + bt.y + db.y;
  float oz = g.z * (1.f + dg.z) * ((v.z - mean) * rstd) + bt.z + db.z;
  float ow = g.w * (1.f + dg.w) * ((v.w - mean) * rstd) + bt.w + db.w;
  ((uint2*)(out + (long)row * DIM_))[lane] = make_uint2(pack2(ox, oy), pack2(oz, ow));
}

// ---------------- tiled GEMM: out[M,N] = A_bf16[M,K] @ W_f32[K,N] + bias ----------------
// EPI 0: bias only, bf16 out
// EPI 1: bias + exact GELU, bf16 out
// EPI 2: bias + res add (in-place ok), f32 out
// EPI 3: proj scatter (window reverse + roll(+4)) + res, f32 out
template <int EPI>
__global__ __launch_bounds__(256) void gemm_kernel(const bf16* __restrict__ A,
    const float* __restrict__ W, const float* __restrict__ bias,
    void* __restrict__ outv, const float* __restrict__ res,
    int M, int N, int K) {
  __shared__ float As[16][65];
  __shared__ float Bs[16][65];
  int tid = threadIdx.x;
  int bm = blockIdx.x * 64, bn = blockIdx.y * 64;
  int tx = tid & 15, ty = tid >> 4;
  int ka = tid & 15, ma = tid >> 4;
  int nb = tid & 63, kb = tid >> 6;
  float acc[4][4] = {};
  for (int kk = 0; kk < K; kk += 16) {
#pragma unroll
    for (int q = 0; q < 4; ++q)
      As[ka][ma + q * 16] = __bfloat162float(A[(long)(bm + ma + q * 16) * K + kk + ka]);
#pragma unroll
    for (int q = 0; q < 4; ++q)
      Bs[kb + q * 4][nb] = W[(long)(kk + kb + q * 4) * N + bn + nb];
    __syncthreads();
#pragma unroll
    for (int k = 0; k < 16; ++k) {
      float a0 = As[k][ty], a1 = As[k][ty + 16], a2 = As[k][ty + 32], a3 = As[k][ty + 48];
      float b0 = Bs[k][tx], b1 = Bs[k][tx + 16], b2 = Bs[k][tx + 32], b3 = Bs[k][tx + 48];
      acc[0][0] += a0 * b0; acc[0][1] += a0 * b1; acc[0][2] += a0 * b2; acc[0][3] += a0 * b3;
      acc[1][0] += a1 * b0; acc[1][1] += a1 * b1; acc[1][2] += a1 * b2; acc[1][3] += a1 * b3;
      acc[2][0] += a2 * b0; acc[2][1] += a2 * b1; acc[2][2] += a2 * b2; acc[2][3] += a2 * b3;
      acc[3][0] += a3 * b0; acc[3][1] += a3 * b1; acc[3][2] += a3 * b2; acc[3][3] += a3 * b3;
    }
    __syncthreads();
  }
#pragma unroll
  for (int i = 0; i < 4; ++i) {
    int row = bm + ty + 16 * i;
    long dst = row;
    if (EPI == 3) {
      int w = row >> 6, n = row & 63;
      int b = w >> 6, wi = (w >> 3) & 7, wj = w & 7;
      int rr = (wi * 8 + (n >> 3) + SHIFT_) & 63;
      int cc = (wj * 8 + (n & 7) + SHIFT_) & 63;
      dst = (long)b * 4096 + rr * 64 + cc;
    }
#pragma unroll
    for (int j = 0; j < 4; ++j) {
      int col = bn + tx + 16 * j;
      float v = acc[i][j] + bias[col];
      if (EPI == 1) v = 0.5f * v * (1.f + erff(v * 0.70710678118654752f));
      if (EPI <= 1) {
        ((bf16*)outv)[(long)row * N + col] = __float2bfloat16(v);
      } else if (EPI == 2) {
        v += res[(long)row * N + col];
        ((float*)outv)[(long)row * N + col] = v;
      } else {
        v += res[dst * DIM_ + col];
        ((float*)outv)[dst * DIM_ + col] = v;
      }
    }
  }
}

// ---------------- attention per (window, head); qkv/out bf16 ----------------
__global__ __launch_bounds__(256) void attn_kernel(const bf16* __restrict__ qkv,
    const float* __restrict__ rpb, bf16* __restrict__ o) {
  __shared__ float qs[64][33];
  __shared__ float ks[64][33];
  __shared__ float vs[64][33];
  __shared__ float S[64][65];
  int wl = blockIdx.x >> 3, h = blockIdx.x & 7;
  int tid = threadIdx.x;
  const float scale = 0.17677669529663689f;  // 1/sqrt(32)
  {
    int n = tid >> 2, f4 = tid & 3;
    long e = (long)(wl * 64 + n) * 768 + h * 32 + f4 * 8;
    uint4 qa = *(const uint4*)(qkv + e);
    uint4 ka4 = *(const uint4*)(qkv + e + 256);
    uint4 va4 = *(const uint4*)(qkv + e + 512);
    int d0 = f4 * 8;
    qs[n][d0 + 0] = u2f_lo(qa.x) * scale; qs[n][d0 + 1] = u2f_hi(qa.x) * scale;
    qs[n][d0 + 2] = u2f_lo(qa.y) * scale; qs[n][d0 + 3] = u2f_hi(qa.y) * scale;
    qs[n][d0 + 4] = u2f_lo(qa.z) * scale; qs[n][d0 + 5] = u2f_hi(qa.z) * scale;
    qs[n][d0 + 6] = u2f_lo(qa.w) * scale; qs[n][d0 + 7] = u2f_hi(qa.w) * scale;
    ks[n][d0 + 0] = u2f_lo(ka4.x); ks[n][d0 + 1] = u2f_hi(ka4.x);
    ks[n][d0 + 2] = u2f_lo(ka4.y); ks[n][d0 + 3] = u2f_hi(ka4.y);
    ks[n][d0 + 4] = u2f_lo(ka4.z); ks[n][d0 + 5] = u2f_hi(ka4.z);
    ks[n][d0 + 6] = u2f_lo(ka4.w); ks[n][d0 + 7] = u2f_hi(ka4.w);
    vs[n][d0 + 0] = u2f_lo(va4.x); vs[n][d0 + 1] = u2f_hi(va4.x);
    vs[n][d0 + 2] = u2f_lo(va4.y); vs[n][d0 + 3] = u2f_hi(va4.y);
    vs[n][d0 + 4] = u2f_lo(va4.z); vs[n][d0 + 5] = u2f_hi(va4.z);
    vs[n][d0 + 6] = u2f_lo(va4.w); vs[n][d0 + 7] = u2f_hi(va4.w);
  }
  __syncthreads();
#pragma unroll
  for (int rep = 0; rep < 16; ++rep) {
    int e = rep * 256 + tid;
    int n = e >> 6, m = e & 63;
    int idx = ((n >> 3) - (m >> 3) + 7) * 15 + ((n & 7) - (m & 7) + 7);
    float acc = rpb[idx * NH_ + h];
#pragma unroll
    for (int d = 0; d < 32; ++d) acc += qs[n][d] * ks[m][d];
    S[n][m] = acc;
  }
  __syncthreads();
  {
    int r = tid >> 2, sub = tid & 3;
    float mx = -1e30f;
#pragma unroll
    for (int q = 0; q < 16; ++q) mx = fmaxf(mx, S[r][sub * 16 + q]);
    mx = fmaxf(mx, __shfl_xor(mx, 1));
    mx = fmaxf(mx, __shfl_xor(mx, 2));
    float sm = 0.f;
#pragma unroll
    for (int q = 0; q < 16; ++q) {
      float e = __expf(S[r][sub * 16 + q] - mx);
      S[r][sub * 16 + q] = e;
      sm += e;
    }
    sm += __shfl_xor(sm, 1);
    sm += __shfl_xor(sm, 2);
    float inv = 1.f / sm;
#pragma unroll
    for (int q = 0; q < 16; ++q) S[r][sub * 16 + q] *= inv;
  }
  __syncthreads();
  {
    int n = tid >> 2, f4 = tid & 3;
    int d0 = f4 * 8;
    float acc[8] = {};
    for (int m = 0; m < 64; ++m) {
      float p = S[n][m];
#pragma unroll
      for (int j = 0; j < 8; ++j) acc[j] += p * vs[m][d0 + j];
    }
    uint4 pk;
    pk.x = pack2(acc[0], acc[1]); pk.y = pack2(acc[2], acc[3]);
    pk.z = pack2(acc[4], acc[5]); pk.w = pack2(acc[6], acc[7]);
    *(uint4*)(o + (long)(wl * 64 + n) * DIM_ + h * 32 + d0) = pk;
  }
}

extern "C" void kernel_launch(void* const* d_in, const int* in_sizes, int n_in,
                              void* d_out, int out_size, void* d_ws, size_t ws_size,
                              hipStream_t stream) {
  const float* x      = (const float*)d_in[0];
  const float* cond   = (const float*)d_in[1];
  const float* gamma1 = (const float*)d_in[4];
  const float* beta1  = (const float*)d_in[5];
  const float* mod1_w = (const float*)d_in[6];
  const float* mod1_b = (const float*)d_in[7];
  const float* qkv_w  = (const float*)d_in[8];
  const float* qkv_b  = (const float*)d_in[9];
  const float* rpb    = (const float*)d_in[10];
  const float* proj_w = (const float*)d_in[11];
  const float* proj_b = (const float*)d_in[12];
  const float* gamma2 = (const float*)d_in[13];
  const float* beta2  = (const float*)d_in[14];
  const float* mod2_w = (const float*)d_in[15];
  const float* mod2_b = (const float*)d_in[16];
  const float* fc1_w  = (const float*)d_in[17];
  const float* fc1_b  = (const float*)d_in[18];
  const float* fc2_w  = (const float*)d_in[19];
  const float* fc2_b  = (const float*)d_in[20];
  float* out = (float*)d_out;

  // workspace layout (67.2 MB total):
  //   mod1: 8192 f32, mod2: 8192 f32        (64 KB)
  //   buf_h: 65536*256 bf16                 (33.5 MB)
  //   chunk: 16384*1024 bf16                (33.5 MB; qkv chunk / hid chunk)
  char* wsb   = (char*)d_ws;
  float* mod1 = (float*)wsb;
  float* mod2 = mod1 + 8192;
  bf16* buf_h = (bf16*)(wsb + 65536);
  bf16* chunk = buf_h + (long)65536 * 256;

  hipLaunchKernelGGL(mod_kernel, dim3(64), dim3(256), 0, stream,
                     cond, mod1_w, mod1_b, mod2_w, mod2_b, mod1, mod2);
  hipLaunchKernelGGL((adaln_kernel<0>), dim3(16384), dim3(256), 0, stream,
                     x, mod1, gamma1, beta1, buf_h);
  for (int c = 0; c < 4; ++c) {
    const bf16* hA = buf_h + (long)c * 16384 * 256;
    hipLaunchKernelGGL((gemm_kernel<0>), dim3(256, 12), dim3(256), 0, stream,
                       hA, qkv_w, qkv_b, (void*)chunk, (const float*)nullptr, 16384, 768, 256);
    hipLaunchKernelGGL(attn_kernel, dim3(2048), dim3(256), 0, stream,
                       chunk, rpb, buf_h + (long)c * 16384 * 256);
  }
  // proj + window-reverse + roll + residual(x) -> d_out (= x1, f32)
  hipLaunchKernelGGL((gemm_kernel<3>), dim3(1024, 4), dim3(256), 0, stream,
                     buf_h, proj_w, proj_b, (void*)out, x, 65536, 256, 256);
  // adaLN2 on x1 -> buf_h (bf16)
  hipLaunchKernelGGL((adaln_kernel<1>), dim3(16384), dim3(256), 0, stream,
                     out, mod2, gamma2, beta2, buf_h);
  for (int c = 0; c < 4; ++c) {
    const bf16* hA = buf_h + (long)c * 16384 * 256;
    float* oc = out + (long)c * 16384 * 256;
    hipLaunchKernelGGL((gemm_kernel<1>), dim3(256, 16), dim3(256), 0, stream,
                       hA, fc1_w, fc1_b, (void*)chunk, (const float*)nullptr, 16384, 1024, 256);
    hipLaunchKernelGGL((gemm_kernel<2>), dim3(256, 4), dim3(256), 0, stream,
                       chunk, fc2_w, fc2_b, (void*)oc, oc, 16384, 256, 1024);
  }
}

// Round 4
// 800.137 us; speedup vs baseline: 2.8499x; 2.8499x over previous
//
#include <hip/hip_runtime.h>
#include <hip/hip_bf16.h>
#include <math.h>

#define SHIFT_ 4
#define NH_ 8
#define DIM_ 256
#define COND_ 128
#define HID_ 1024

typedef __hip_bfloat16 bf16;
typedef __attribute__((ext_vector_type(8))) short short8;
typedef __attribute__((ext_vector_type(4))) float f32x4;

__device__ inline float u2f_lo(unsigned u) { return __uint_as_float(u << 16); }
__device__ inline float u2f_hi(unsigned u) { return __uint_as_float(u & 0xFFFF0000u); }
__device__ inline unsigned pack2(float a, float b) {
  bf16 x = __float2bfloat16(a), y = __float2bfloat16(b);
  unsigned short ux = *(unsigned short*)&x, uy = *(unsigned short*)&y;
  return (unsigned)ux | ((unsigned)uy << 16);
}

#define GL_LDS16(g, l) __builtin_amdgcn_global_load_lds( \
    (const __attribute__((address_space(1))) unsigned*)(g), \
    (__attribute__((address_space(3))) unsigned*)(l), 16, 0, 0)

// ---------------- weight prep: wt[n*K+k] = bf16(w[k*N+n]) ----------------
__global__ __launch_bounds__(256) void wprep_kernel(const float* __restrict__ w,
    bf16* __restrict__ wt, int K, int N) {
  int idx = blockIdx.x * 256 + threadIdx.x;
  if (idx >= K * N) return;
  int k = idx / N, n = idx - k * N;
  wt[(long)n * K + k] = __float2bfloat16(w[idx]);
}

// ---------------- mod = cond @ w + b  (both mod1 and mod2) ----------------
__global__ __launch_bounds__(256) void mod_kernel(const float* __restrict__ cond,
    const float* __restrict__ w1, const float* __restrict__ b1,
    const float* __restrict__ w2, const float* __restrict__ b2,
    float* __restrict__ mod1, float* __restrict__ mod2) {
  int gid = blockIdx.x * 256 + threadIdx.x;
  int sel = gid >> 13;
  int r   = gid & 8191;
  int b   = r >> 9;
  int c   = r & 511;
  const float* w  = sel ? w2 : w1;
  const float* bb = sel ? b2 : b1;
  const float* cp = cond + b * COND_;
  float acc = bb[c];
#pragma unroll 4
  for (int k = 0; k < COND_; ++k) acc += cp[k] * w[k * 512 + c];
  (sel ? mod2 : mod1)[b * 512 + c] = acc;
}

// ---------------- adaLN -> bf16 out (+ optional shift-window gather) ----------------
template <int MODE>
__global__ __launch_bounds__(256) void adaln_kernel(const float* __restrict__ x,
    const float* __restrict__ mod, const float* __restrict__ gamma,
    const float* __restrict__ beta, bf16* __restrict__ out) {
  int lane = threadIdx.x & 63;
  int row  = blockIdx.x * 4 + (threadIdx.x >> 6);
  int b, src;
  if (MODE == 0) {
    int w = row >> 6, n = row & 63;
    b = w >> 6;
    int wi = (w >> 3) & 7, wj = w & 7;
    int rr = (wi * 8 + (n >> 3) + SHIFT_) & 63;
    int cc = (wj * 8 + (n & 7) + SHIFT_) & 63;
    src = rr * 64 + cc;
  } else {
    b   = row >> 12;
    src = row & 4095;
  }
  float4 v = ((const float4*)(x + ((long)b * 4096 + src) * DIM_))[lane];
  float s  = v.x + v.y + v.z + v.w;
  float sq = v.x * v.x + v.y * v.y + v.z * v.z + v.w * v.w;
#pragma unroll
  for (int off = 32; off >= 1; off >>= 1) {
    s  += __shfl_xor(s, off);
    sq += __shfl_xor(sq, off);
  }
  float mean = s * (1.f / DIM_);
  float var  = sq * (1.f / DIM_) - mean * mean;
  float rstd = rsqrtf(var + 1e-6f);
  float4 g  = ((const float4*)gamma)[lane];
  float4 bt = ((const float4*)beta)[lane];
  float4 dg = ((const float4*)(mod + b * 512))[lane];
  float4 db = ((const float4*)(mod + b * 512 + 256))[lane];
  float ox = g.x * (1.f + dg.x) * ((v.x - mean) * rstd) + bt.x + db.x;
  float oy = g.y * (1.f + dg.y) * ((v.y - mean) * rstd) + bt.y + db.y;
  float oz = g.z * (1.f + dg.z) * ((v.z - mean) * rstd) + bt.z + db.z;
  float ow = g.w * (1.f + dg.w) * ((v.w - mean) * rstd) + bt.w + db.w;
  ((uint2*)(out + (long)row * DIM_))[lane] = make_uint2(pack2(ox, oy), pack2(oz, ow));
}

// ---------------- MFMA GEMM: out[M,N] = A_bf16[M,K] @ Wt_bf16[N,K]^T + bias ----------
// 128x128 tile, BK=32, 4 waves (2x2 of 64x64), 16x16x32 bf16 MFMA.
// EPI 0: bias, bf16 out | 1: bias+GELU, bf16 out | 2: bias+res, f32 out
// EPI 3: proj scatter (window reverse + roll(+4)) + res, f32 out
template <int EPI>
__global__ __launch_bounds__(256) void gemm_mfma(const bf16* __restrict__ A,
    const bf16* __restrict__ Wt, const float* __restrict__ bias,
    void* __restrict__ outv, const float* __restrict__ res,
    int M, int N, int K) {
  __shared__ __align__(16) bf16 As[128 * 32];
  __shared__ __align__(16) bf16 Bs[128 * 32];
  int tid = threadIdx.x;
  int bm = blockIdx.x * 128, bn = blockIdx.y * 128;
  int lane = tid & 63, wid = tid >> 6;
  int wm = (wid >> 1) * 64, wn = (wid & 1) * 64;
  int l15 = lane & 15, kg = (lane >> 4) * 8;

  f32x4 acc[4][4];
#pragma unroll
  for (int i = 0; i < 4; ++i)
#pragma unroll
    for (int j = 0; j < 4; ++j) acc[i][j] = (f32x4){0.f, 0.f, 0.f, 0.f};

  int o1 = tid * 16;          // LDS byte offset, round 1 (0..4095)
  int o2 = o1 + 4096;         // round 2
  int row1 = o1 >> 6, c1 = o1 & 63;   // 64 B per 32-elem bf16 row
  int row2 = o2 >> 6, c2 = o2 & 63;

  for (int kk = 0; kk < K; kk += 32) {
    GL_LDS16((const char*)A  + ((long)(bm + row1) * K + kk) * 2 + c1, (char*)As + o1);
    GL_LDS16((const char*)A  + ((long)(bm + row2) * K + kk) * 2 + c2, (char*)As + o2);
    GL_LDS16((const char*)Wt + ((long)(bn + row1) * K + kk) * 2 + c1, (char*)Bs + o1);
    GL_LDS16((const char*)Wt + ((long)(bn + row2) * K + kk) * 2 + c2, (char*)Bs + o2);
    __syncthreads();
    short8 af[4], bfr[4];
#pragma unroll
    for (int mi = 0; mi < 4; ++mi)
      af[mi] = *(const short8*)(As + (wm + mi * 16 + l15) * 32 + kg);
#pragma unroll
    for (int ni = 0; ni < 4; ++ni)
      bfr[ni] = *(const short8*)(Bs + (wn + ni * 16 + l15) * 32 + kg);
#pragma unroll
    for (int mi = 0; mi < 4; ++mi)
#pragma unroll
      for (int ni = 0; ni < 4; ++ni)
        acc[mi][ni] = __builtin_amdgcn_mfma_f32_16x16x32_bf16(af[mi], bfr[ni], acc[mi][ni], 0, 0, 0);
    __syncthreads();
  }

  int col0 = bn + wn + l15;
  int r0 = (lane >> 4) * 4;
#pragma unroll
  for (int mi = 0; mi < 4; ++mi) {
#pragma unroll
    for (int r = 0; r < 4; ++r) {
      int row = bm + wm + mi * 16 + r0 + r;
      long dst = row;
      if (EPI == 3) {
        int w = row >> 6, n = row & 63;
        int b = w >> 6, wi = (w >> 3) & 7, wj = w & 7;
        int rr = (wi * 8 + (n >> 3) + SHIFT_) & 63;
        int cc = (wj * 8 + (n & 7) + SHIFT_) & 63;
        dst = (long)b * 4096 + rr * 64 + cc;
      }
#pragma unroll
      for (int ni = 0; ni < 4; ++ni) {
        int col = col0 + ni * 16;
        float v = acc[mi][ni][r] + bias[col];
        if (EPI == 1) v = 0.5f * v * (1.f + erff(v * 0.70710678118654752f));
        if (EPI <= 1) {
          ((bf16*)outv)[(long)row * N + col] = __float2bfloat16(v);
        } else if (EPI == 2) {
          ((float*)outv)[(long)row * N + col] = v + res[(long)row * N + col];
        } else {
          ((float*)outv)[dst * DIM_ + col] = v + res[dst * DIM_ + col];
        }
      }
    }
  }
}

// ---------------- attention per (window, head); qkv/out bf16 ----------------
__global__ __launch_bounds__(256) void attn_kernel(const bf16* __restrict__ qkv,
    const float* __restrict__ rpb, bf16* __restrict__ o) {
  __shared__ float qs[64][33];
  __shared__ float ks[64][33];
  __shared__ float vs[64][33];
  __shared__ float S[64][65];
  int wl = blockIdx.x >> 3, h = blockIdx.x & 7;
  int tid = threadIdx.x;
  const float scale = 0.17677669529663689f;  // 1/sqrt(32)
  {
    int n = tid >> 2, f4 = tid & 3;
    long e = (long)(wl * 64 + n) * 768 + h * 32 + f4 * 8;
    uint4 qa = *(const uint4*)(qkv + e);
    uint4 ka4 = *(const uint4*)(qkv + e + 256);
    uint4 va4 = *(const uint4*)(qkv + e + 512);
    int d0 = f4 * 8;
    qs[n][d0 + 0] = u2f_lo(qa.x) * scale; qs[n][d0 + 1] = u2f_hi(qa.x) * scale;
    qs[n][d0 + 2] = u2f_lo(qa.y) * scale; qs[n][d0 + 3] = u2f_hi(qa.y) * scale;
    qs[n][d0 + 4] = u2f_lo(qa.z) * scale; qs[n][d0 + 5] = u2f_hi(qa.z) * scale;
    qs[n][d0 + 6] = u2f_lo(qa.w) * scale; qs[n][d0 + 7] = u2f_hi(qa.w) * scale;
    ks[n][d0 + 0] = u2f_lo(ka4.x); ks[n][d0 + 1] = u2f_hi(ka4.x);
    ks[n][d0 + 2] = u2f_lo(ka4.y); ks[n][d0 + 3] = u2f_hi(ka4.y);
    ks[n][d0 + 4] = u2f_lo(ka4.z); ks[n][d0 + 5] = u2f_hi(ka4.z);
    ks[n][d0 + 6] = u2f_lo(ka4.w); ks[n][d0 + 7] = u2f_hi(ka4.w);
    vs[n][d0 + 0] = u2f_lo(va4.x); vs[n][d0 + 1] = u2f_hi(va4.x);
    vs[n][d0 + 2] = u2f_lo(va4.y); vs[n][d0 + 3] = u2f_hi(va4.y);
    vs[n][d0 + 4] = u2f_lo(va4.z); vs[n][d0 + 5] = u2f_hi(va4.z);
    vs[n][d0 + 6] = u2f_lo(va4.w); vs[n][d0 + 7] = u2f_hi(va4.w);
  }
  __syncthreads();
#pragma unroll
  for (int rep = 0; rep < 16; ++rep) {
    int e = rep * 256 + tid;
    int n = e >> 6, m = e & 63;
    int idx = ((n >> 3) - (m >> 3) + 7) * 15 + ((n & 7) - (m & 7) + 7);
    float acc = rpb[idx * NH_ + h];
#pragma unroll
    for (int d = 0; d < 32; ++d) acc += qs[n][d] * ks[m][d];
    S[n][m] = acc;
  }
  __syncthreads();
  {
    int r = tid >> 2, sub = tid & 3;
    float mx = -1e30f;
#pragma unroll
    for (int q = 0; q < 16; ++q) mx = fmaxf(mx, S[r][sub * 16 + q]);
    mx = fmaxf(mx, __shfl_xor(mx, 1));
    mx = fmaxf(mx, __shfl_xor(mx, 2));
    float sm = 0.f;
#pragma unroll
    for (int q = 0; q < 16; ++q) {
      float e = __expf(S[r][sub * 16 + q] - mx);
      S[r][sub * 16 + q] = e;
      sm += e;
    }
    sm += __shfl_xor(sm, 1);
    sm += __shfl_xor(sm, 2);
    float inv = 1.f / sm;
#pragma unroll
    for (int q = 0; q < 16; ++q) S[r][sub * 16 + q] *= inv;
  }
  __syncthreads();
  {
    int n = tid >> 2, f4 = tid & 3;
    int d0 = f4 * 8;
    float acc[8] = {};
    for (int m = 0; m < 64; ++m) {
      float p = S[n][m];
#pragma unroll
      for (int j = 0; j < 8; ++j) acc[j] += p * vs[m][d0 + j];
    }
    uint4 pk;
    pk.x = pack2(acc[0], acc[1]); pk.y = pack2(acc[2], acc[3]);
    pk.z = pack2(acc[4], acc[5]); pk.w = pack2(acc[6], acc[7]);
    *(uint4*)(o + (long)(wl * 64 + n) * DIM_ + h * 32 + d0) = pk;
  }
}

extern "C" void kernel_launch(void* const* d_in, const int* in_sizes, int n_in,
                              void* d_out, int out_size, void* d_ws, size_t ws_size,
                              hipStream_t stream) {
  const float* x      = (const float*)d_in[0];
  const float* cond   = (const float*)d_in[1];
  const float* gamma1 = (const float*)d_in[4];
  const float* beta1  = (const float*)d_in[5];
  const float* mod1_w = (const float*)d_in[6];
  const float* mod1_b = (const float*)d_in[7];
  const float* qkv_w  = (const float*)d_in[8];
  const float* qkv_b  = (const float*)d_in[9];
  const float* rpb    = (const float*)d_in[10];
  const float* proj_w = (const float*)d_in[11];
  const float* proj_b = (const float*)d_in[12];
  const float* gamma2 = (const float*)d_in[13];
  const float* beta2  = (const float*)d_in[14];
  const float* mod2_w = (const float*)d_in[15];
  const float* mod2_b = (const float*)d_in[16];
  const float* fc1_w  = (const float*)d_in[17];
  const float* fc1_b  = (const float*)d_in[18];
  const float* fc2_w  = (const float*)d_in[19];
  const float* fc2_b  = (const float*)d_in[20];
  float* out = (float*)d_out;

  // workspace layout (~68.7 MB):
  //   mod1/mod2: 2*8192 f32 (64 KB)
  //   qkv_wt [768][256] bf16, proj_wt [256][256], fc1_wt [1024][256], fc2_wt [256][1024]
  //   buf_h: 65536*256 bf16 (33.5 MB)
  //   chunk: 16384*1024 bf16 (33.5 MB)
  char* wsb    = (char*)d_ws;
  float* mod1  = (float*)wsb;
  float* mod2  = mod1 + 8192;
  bf16* qkv_wt = (bf16*)(wsb + 65536);
  bf16* proj_wt = qkv_wt + 256 * 768;
  bf16* fc1_wt  = proj_wt + 256 * 256;
  bf16* fc2_wt  = fc1_wt + 256 * 1024;
  bf16* buf_h   = fc2_wt + 1024 * 256;
  bf16* chunk   = buf_h + (long)65536 * 256;

  hipLaunchKernelGGL(wprep_kernel, dim3(768), dim3(256), 0, stream, qkv_w, qkv_wt, 256, 768);
  hipLaunchKernelGGL(wprep_kernel, dim3(256), dim3(256), 0, stream, proj_w, proj_wt, 256, 256);
  hipLaunchKernelGGL(wprep_kernel, dim3(1024), dim3(256), 0, stream, fc1_w, fc1_wt, 256, 1024);
  hipLaunchKernelGGL(wprep_kernel, dim3(1024), dim3(256), 0, stream, fc2_w, fc2_wt, 1024, 256);

  hipLaunchKernelGGL(mod_kernel, dim3(64), dim3(256), 0, stream,
                     cond, mod1_w, mod1_b, mod2_w, mod2_b, mod1, mod2);
  hipLaunchKernelGGL((adaln_kernel<0>), dim3(16384), dim3(256), 0, stream,
                     x, mod1, gamma1, beta1, buf_h);
  for (int c = 0; c < 4; ++c) {
    const bf16* hA = buf_h + (long)c * 16384 * 256;
    hipLaunchKernelGGL((gemm_mfma<0>), dim3(128, 6), dim3(256), 0, stream,
                       hA, qkv_wt, qkv_b, (void*)chunk, (const float*)nullptr, 16384, 768, 256);
    hipLaunchKernelGGL(attn_kernel, dim3(2048), dim3(256), 0, stream,
                       chunk, rpb, buf_h + (long)c * 16384 * 256);
  }
  // proj + window-reverse + roll + residual(x) -> d_out (= x1, f32)
  hipLaunchKernelGGL((gemm_mfma<3>), dim3(512, 2), dim3(256), 0, stream,
                     buf_h, proj_wt, proj_b, (void*)out, x, 65536, 256, 256);
  // adaLN2 on x1 -> buf_h (bf16)
  hipLaunchKernelGGL((adaln_kernel<1>), dim3(16384), dim3(256), 0, stream,
                     out, mod2, gamma2, beta2, buf_h);
  for (int c = 0; c < 4; ++c) {
    const bf16* hA = buf_h + (long)c * 16384 * 256;
    float* oc = out + (long)c * 16384 * 256;
    hipLaunchKernelGGL((gemm_mfma<1>), dim3(128, 8), dim3(256), 0, stream,
                       hA, fc1_wt, fc1_b, (void*)chunk, (const float*)nullptr, 16384, 1024, 256);
    hipLaunchKernelGGL((gemm_mfma<2>), dim3(128, 2), dim3(256), 0, stream,
                       chunk, fc2_wt, fc2_b, (void*)oc, oc, 16384, 256, 1024);
  }
}

// Round 5
// 582.349 us; speedup vs baseline: 3.9158x; 1.3740x over previous
//
#include <hip/hip_runtime.h>
#include <hip/hip_bf16.h>
#include <math.h>

#define SHIFT_ 4
#define NH_ 8
#define DIM_ 256
#define COND_ 128
#define HID_ 1024

typedef __hip_bfloat16 bf16;
typedef __attribute__((ext_vector_type(8))) short short8;
typedef __attribute__((ext_vector_type(4))) float f32x4;

__device__ inline unsigned pack2(float a, float b) {
  bf16 x = __float2bfloat16(a), y = __float2bfloat16(b);
  unsigned short ux = *(unsigned short*)&x, uy = *(unsigned short*)&y;
  return (unsigned)ux | ((unsigned)uy << 16);
}

#define GL_LDS16(g, l) __builtin_amdgcn_global_load_lds( \
    (const __attribute__((address_space(1))) unsigned*)(g), \
    (__attribute__((address_space(3))) unsigned*)(l), 16, 0, 0)

// ---------------- weight prep: wt[n*K+k] = bf16(w[k*N+n]) ----------------
__global__ __launch_bounds__(256) void wprep_kernel(const float* __restrict__ w,
    bf16* __restrict__ wt, int K, int N) {
  int idx = blockIdx.x * 256 + threadIdx.x;
  if (idx >= K * N) return;
  int k = idx / N, n = idx - k * N;
  wt[(long)n * K + k] = __float2bfloat16(w[idx]);
}

// ---------------- rel-pos bias in MFMA C-fragment order ----------------
// layout: [h][mi][ni][lane][r], n = 16*mi + (lane>>4)*4 + r, m = 16*ni + (lane&15)
__global__ __launch_bounds__(256) void bias_prep(const float* __restrict__ rpb,
    float* __restrict__ bfr) {
  int t = blockIdx.x * 256 + threadIdx.x;   // 0..8191
  int h = t >> 10, mi = (t >> 8) & 3, ni = (t >> 6) & 3, lane = t & 63;
  int g = lane >> 4, l15 = lane & 15;
  int m = 16 * ni + l15;
#pragma unroll
  for (int r = 0; r < 4; ++r) {
    int n = 16 * mi + g * 4 + r;
    int idx = ((n >> 3) - (m >> 3) + 7) * 15 + ((n & 7) - (m & 7) + 7);
    bfr[(((h * 4 + mi) * 4 + ni) * 64 + lane) * 4 + r] = rpb[idx * NH_ + h];
  }
}

// ---------------- mod = cond @ w + b ----------------
__global__ __launch_bounds__(256) void mod_kernel(const float* __restrict__ cond,
    const float* __restrict__ w1, const float* __restrict__ b1,
    const float* __restrict__ w2, const float* __restrict__ b2,
    float* __restrict__ mod1, float* __restrict__ mod2) {
  int gid = blockIdx.x * 256 + threadIdx.x;
  int sel = gid >> 13;
  int r   = gid & 8191;
  int b   = r >> 9;
  int c   = r & 511;
  const float* w  = sel ? w2 : w1;
  const float* bb = sel ? b2 : b1;
  const float* cp = cond + b * COND_;
  float acc = bb[c];
#pragma unroll 4
  for (int k = 0; k < COND_; ++k) acc += cp[k] * w[k * 512 + c];
  (sel ? mod2 : mod1)[b * 512 + c] = acc;
}

// ---------------- adaLN -> bf16 out (+ optional shift-window gather) ----------------
template <int MODE>
__global__ __launch_bounds__(256) void adaln_kernel(const float* __restrict__ x,
    const float* __restrict__ mod, const float* __restrict__ gamma,
    const float* __restrict__ beta, bf16* __restrict__ out) {
  int lane = threadIdx.x & 63;
  int row  = blockIdx.x * 4 + (threadIdx.x >> 6);
  int b, src;
  if (MODE == 0) {
    int w = row >> 6, n = row & 63;
    b = w >> 6;
    int wi = (w >> 3) & 7, wj = w & 7;
    int rr = (wi * 8 + (n >> 3) + SHIFT_) & 63;
    int cc = (wj * 8 + (n & 7) + SHIFT_) & 63;
    src = rr * 64 + cc;
  } else {
    b   = row >> 12;
    src = row & 4095;
  }
  float4 v = ((const float4*)(x + ((long)b * 4096 + src) * DIM_))[lane];
  float s  = v.x + v.y + v.z + v.w;
  float sq = v.x * v.x + v.y * v.y + v.z * v.z + v.w * v.w;
#pragma unroll
  for (int off = 32; off >= 1; off >>= 1) {
    s  += __shfl_xor(s, off);
    sq += __shfl_xor(sq, off);
  }
  float mean = s * (1.f / DIM_);
  float var  = sq * (1.f / DIM_) - mean * mean;
  float rstd = rsqrtf(var + 1e-6f);
  float4 g  = ((const float4*)gamma)[lane];
  float4 bt = ((const float4*)beta)[lane];
  float4 dg = ((const float4*)(mod + b * 512))[lane];
  float4 db = ((const float4*)(mod + b * 512 + 256))[lane];
  float ox = g.x * (1.f + dg.x) * ((v.x - mean) * rstd) + bt.x + db.x;
  float oy = g.y * (1.f + dg.y) * ((v.y - mean) * rstd) + bt.y + db.y;
  float oz = g.z * (1.f + dg.z) * ((v.z - mean) * rstd) + bt.z + db.z;
  float ow = g.w * (1.f + dg.w) * ((v.w - mean) * rstd) + bt.w + db.w;
  ((uint2*)(out + (long)row * DIM_))[lane] = make_uint2(pack2(ox, oy), pack2(oz, ow));
}

// ---------------- MFMA GEMM: out[M,N] = A_bf16[M,K] @ Wt_bf16[N,K]^T + bias ----------
// EPI 0: bias, bf16 out | 1: bias+GELU, bf16 out | 2: bias+res, f32 out
// EPI 3: proj scatter + res, f32 out | 4: bias, bf16 out, cols<256 scaled by 1/sqrt(32)
template <int EPI>
__global__ __launch_bounds__(256) void gemm_mfma(const bf16* __restrict__ A,
    const bf16* __restrict__ Wt, const float* __restrict__ bias,
    void* __restrict__ outv, const float* __restrict__ res,
    int M, int N, int K) {
  __shared__ __align__(16) bf16 As[128 * 32];
  __shared__ __align__(16) bf16 Bs[128 * 32];
  int tid = threadIdx.x;
  int bm = blockIdx.x * 128, bn = blockIdx.y * 128;
  int lane = tid & 63, wid = tid >> 6;
  int wm = (wid >> 1) * 64, wn = (wid & 1) * 64;
  int l15 = lane & 15, kg = (lane >> 4) * 8;

  f32x4 acc[4][4];
#pragma unroll
  for (int i = 0; i < 4; ++i)
#pragma unroll
    for (int j = 0; j < 4; ++j) acc[i][j] = (f32x4){0.f, 0.f, 0.f, 0.f};

  int o1 = tid * 16;
  int o2 = o1 + 4096;
  int row1 = o1 >> 6, c1 = o1 & 63;
  int row2 = o2 >> 6, c2 = o2 & 63;

  for (int kk = 0; kk < K; kk += 32) {
    GL_LDS16((const char*)A  + ((long)(bm + row1) * K + kk) * 2 + c1, (char*)As + o1);
    GL_LDS16((const char*)A  + ((long)(bm + row2) * K + kk) * 2 + c2, (char*)As + o2);
    GL_LDS16((const char*)Wt + ((long)(bn + row1) * K + kk) * 2 + c1, (char*)Bs + o1);
    GL_LDS16((const char*)Wt + ((long)(bn + row2) * K + kk) * 2 + c2, (char*)Bs + o2);
    __syncthreads();
    short8 af[4], bfr[4];
#pragma unroll
    for (int mi = 0; mi < 4; ++mi)
      af[mi] = *(const short8*)(As + (wm + mi * 16 + l15) * 32 + kg);
#pragma unroll
    for (int ni = 0; ni < 4; ++ni)
      bfr[ni] = *(const short8*)(Bs + (wn + ni * 16 + l15) * 32 + kg);
#pragma unroll
    for (int mi = 0; mi < 4; ++mi)
#pragma unroll
      for (int ni = 0; ni < 4; ++ni)
        acc[mi][ni] = __builtin_amdgcn_mfma_f32_16x16x32_bf16(af[mi], bfr[ni], acc[mi][ni], 0, 0, 0);
    __syncthreads();
  }

  int col0 = bn + wn + l15;
  int r0 = (lane >> 4) * 4;
#pragma unroll
  for (int mi = 0; mi < 4; ++mi) {
#pragma unroll
    for (int r = 0; r < 4; ++r) {
      int row = bm + wm + mi * 16 + r0 + r;
      long dst = row;
      if (EPI == 3) {
        int w = row >> 6, n = row & 63;
        int b = w >> 6, wi = (w >> 3) & 7, wj = w & 7;
        int rr = (wi * 8 + (n >> 3) + SHIFT_) & 63;
        int cc = (wj * 8 + (n & 7) + SHIFT_) & 63;
        dst = (long)b * 4096 + rr * 64 + cc;
      }
#pragma unroll
      for (int ni = 0; ni < 4; ++ni) {
        int col = col0 + ni * 16;
        float v = acc[mi][ni][r] + bias[col];
        if (EPI == 1) v = 0.5f * v * (1.f + erff(v * 0.70710678118654752f));
        if (EPI == 4 && col < 256) v *= 0.17677669529663689f;
        if (EPI <= 1 || EPI == 4) {
          ((bf16*)outv)[(long)row * N + col] = __float2bfloat16(v);
        } else if (EPI == 2) {
          ((float*)outv)[(long)row * N + col] = v + res[(long)row * N + col];
        } else {
          ((float*)outv)[dst * DIM_ + col] = v + res[dst * DIM_ + col];
        }
      }
    }
  }
}

// ---------------- MFMA attention: block = 1 window, 4 waves, 2 heads/wave ------------
// S = Q @ K^T (acc init = rel-pos bias fragments), in-register softmax,
// P (bf16, LDS [64][72]) @ V^T (LDS [32][72]) -> O, 1/sum deferred to epilogue.
__global__ __launch_bounds__(256) void attn_mfma(const bf16* __restrict__ qkv,
    const float* __restrict__ bias_frag, bf16* __restrict__ o) {
  __shared__ __align__(16) bf16 Pl[4][64 * 72];
  __shared__ __align__(16) bf16 Vtl[4][32 * 72];
  int tid = threadIdx.x;
  int wave = tid >> 6, lane = tid & 63;
  int l15 = lane & 15, g = lane >> 4;
  int wl = blockIdx.x;
  bf16* P  = Pl[wave];
  bf16* VT = Vtl[wave];

#pragma unroll
  for (int hh = 0; hh < 2; ++hh) {
    int h = wave + hh * 4;
    const bf16* base = qkv + (long)wl * 64 * 768 + h * 32;

    __syncthreads();  // protect VT/P vs previous iteration's reads

    // ---- stage V^T: VT[d][m] from V[m][d] ----
#pragma unroll
    for (int t = 0; t < 4; ++t) {
      int m  = t * 16 + (lane >> 2);
      int d0 = (lane & 3) * 8;
      short8 v = *(const short8*)(base + (long)m * 768 + 512 + d0);
#pragma unroll
      for (int j = 0; j < 8; ++j) VT[(d0 + j) * 72 + m] = ((const bf16*)&v)[j];
    }

    // ---- Q/K fragments direct from global ----
    short8 aq[4], bk[4];
#pragma unroll
    for (int mi = 0; mi < 4; ++mi)
      aq[mi] = *(const short8*)(base + (long)(l15 + 16 * mi) * 768 + g * 8);
#pragma unroll
    for (int ni = 0; ni < 4; ++ni)
      bk[ni] = *(const short8*)(base + (long)(l15 + 16 * ni) * 768 + 256 + g * 8);

    // ---- S = Q@K^T + bias (acc init = bias fragment) ----
    f32x4 s[4][4];
#pragma unroll
    for (int mi = 0; mi < 4; ++mi)
#pragma unroll
      for (int ni = 0; ni < 4; ++ni)
        s[mi][ni] = *(const f32x4*)(bias_frag + (((h * 4 + mi) * 4 + ni) * 64 + lane) * 4);
#pragma unroll
    for (int mi = 0; mi < 4; ++mi)
#pragma unroll
      for (int ni = 0; ni < 4; ++ni)
        s[mi][ni] = __builtin_amdgcn_mfma_f32_16x16x32_bf16(aq[mi], bk[ni], s[mi][ni], 0, 0, 0);

    // ---- in-register softmax over m (cols l15 + regs ni); rows = fragment rows ----
    float inv[4][4];
#pragma unroll
    for (int mi = 0; mi < 4; ++mi) {
#pragma unroll
      for (int r = 0; r < 4; ++r) {
        float mx = fmaxf(fmaxf(s[mi][0][r], s[mi][1][r]), fmaxf(s[mi][2][r], s[mi][3][r]));
        mx = fmaxf(mx, __shfl_xor(mx, 1));
        mx = fmaxf(mx, __shfl_xor(mx, 2));
        mx = fmaxf(mx, __shfl_xor(mx, 4));
        mx = fmaxf(mx, __shfl_xor(mx, 8));
        float e0 = __expf(s[mi][0][r] - mx);
        float e1 = __expf(s[mi][1][r] - mx);
        float e2 = __expf(s[mi][2][r] - mx);
        float e3 = __expf(s[mi][3][r] - mx);
        int n = 16 * mi + g * 4 + r;
        P[n * 72 + l15 +  0] = __float2bfloat16(e0);
        P[n * 72 + l15 + 16] = __float2bfloat16(e1);
        P[n * 72 + l15 + 32] = __float2bfloat16(e2);
        P[n * 72 + l15 + 48] = __float2bfloat16(e3);
        float sm = (e0 + e1) + (e2 + e3);
        sm += __shfl_xor(sm, 1);
        sm += __shfl_xor(sm, 2);
        sm += __shfl_xor(sm, 4);
        sm += __shfl_xor(sm, 8);
        inv[mi][r] = 1.f / sm;
      }
    }

    __syncthreads();  // P/VT visible before fragment reads

    // ---- O = P @ V^T ----
    f32x4 ov[4][2];
#pragma unroll
    for (int mi = 0; mi < 4; ++mi)
#pragma unroll
      for (int ni = 0; ni < 2; ++ni) ov[mi][ni] = (f32x4){0.f, 0.f, 0.f, 0.f};
#pragma unroll
    for (int kt = 0; kt < 2; ++kt) {
      short8 ap[4], bv[2];
#pragma unroll
      for (int mi = 0; mi < 4; ++mi)
        ap[mi] = *(const short8*)(P + (l15 + 16 * mi) * 72 + kt * 32 + g * 8);
#pragma unroll
      for (int ni = 0; ni < 2; ++ni)
        bv[ni] = *(const short8*)(VT + (l15 + 16 * ni) * 72 + kt * 32 + g * 8);
#pragma unroll
      for (int mi = 0; mi < 4; ++mi)
#pragma unroll
        for (int ni = 0; ni < 2; ++ni)
          ov[mi][ni] = __builtin_amdgcn_mfma_f32_16x16x32_bf16(ap[mi], bv[ni], ov[mi][ni], 0, 0, 0);
    }

    // ---- epilogue: scale by 1/sum, write bf16 ----
#pragma unroll
    for (int mi = 0; mi < 4; ++mi)
#pragma unroll
      for (int ni = 0; ni < 2; ++ni)
#pragma unroll
        for (int r = 0; r < 4; ++r) {
          int n = 16 * mi + g * 4 + r;
          int d = l15 + 16 * ni;
          o[(long)(wl * 64 + n) * DIM_ + h * 32 + d] =
              __float2bfloat16(ov[mi][ni][r] * inv[mi][r]);
        }
  }
}

extern "C" void kernel_launch(void* const* d_in, const int* in_sizes, int n_in,
                              void* d_out, int out_size, void* d_ws, size_t ws_size,
                              hipStream_t stream) {
  const float* x      = (const float*)d_in[0];
  const float* cond   = (const float*)d_in[1];
  const float* gamma1 = (const float*)d_in[4];
  const float* beta1  = (const float*)d_in[5];
  const float* mod1_w = (const float*)d_in[6];
  const float* mod1_b = (const float*)d_in[7];
  const float* qkv_w  = (const float*)d_in[8];
  const float* qkv_b  = (const float*)d_in[9];
  const float* rpb    = (const float*)d_in[10];
  const float* proj_w = (const float*)d_in[11];
  const float* proj_b = (const float*)d_in[12];
  const float* gamma2 = (const float*)d_in[13];
  const float* beta2  = (const float*)d_in[14];
  const float* mod2_w = (const float*)d_in[15];
  const float* mod2_b = (const float*)d_in[16];
  const float* fc1_w  = (const float*)d_in[17];
  const float* fc1_b  = (const float*)d_in[18];
  const float* fc2_w  = (const float*)d_in[19];
  const float* fc2_b  = (const float*)d_in[20];
  float* out = (float*)d_out;

  // workspace layout (~68.8 MB)
  char* wsb     = (char*)d_ws;
  float* mod1   = (float*)wsb;
  float* mod2   = mod1 + 8192;
  bf16* qkv_wt  = (bf16*)(wsb + 65536);
  bf16* proj_wt = qkv_wt + 256 * 768;
  bf16* fc1_wt  = proj_wt + 256 * 256;
  bf16* fc2_wt  = fc1_wt + 256 * 1024;
  float* bias_frag = (float*)(fc2_wt + 1024 * 256);   // 32768 f32 = 128 KB
  bf16* buf_h   = (bf16*)(bias_frag + 32768);
  bf16* chunk   = buf_h + (long)65536 * 256;

  hipLaunchKernelGGL(wprep_kernel, dim3(768), dim3(256), 0, stream, qkv_w, qkv_wt, 256, 768);
  hipLaunchKernelGGL(wprep_kernel, dim3(256), dim3(256), 0, stream, proj_w, proj_wt, 256, 256);
  hipLaunchKernelGGL(wprep_kernel, dim3(1024), dim3(256), 0, stream, fc1_w, fc1_wt, 256, 1024);
  hipLaunchKernelGGL(wprep_kernel, dim3(1024), dim3(256), 0, stream, fc2_w, fc2_wt, 1024, 256);
  hipLaunchKernelGGL(bias_prep, dim3(32), dim3(256), 0, stream, rpb, bias_frag);

  hipLaunchKernelGGL(mod_kernel, dim3(64), dim3(256), 0, stream,
                     cond, mod1_w, mod1_b, mod2_w, mod2_b, mod1, mod2);
  hipLaunchKernelGGL((adaln_kernel<0>), dim3(16384), dim3(256), 0, stream,
                     x, mod1, gamma1, beta1, buf_h);
  for (int c = 0; c < 4; ++c) {
    const bf16* hA = buf_h + (long)c * 16384 * 256;
    hipLaunchKernelGGL((gemm_mfma<4>), dim3(128, 6), dim3(256), 0, stream,
                       hA, qkv_wt, qkv_b, (void*)chunk, (const float*)nullptr, 16384, 768, 256);
    hipLaunchKernelGGL(attn_mfma, dim3(256), dim3(256), 0, stream,
                       chunk, bias_frag, buf_h + (long)c * 16384 * 256);
  }
  // proj + window-reverse + roll + residual(x) -> d_out (= x1, f32)
  hipLaunchKernelGGL((gemm_mfma<3>), dim3(512, 2), dim3(256), 0, stream,
                     buf_h, proj_wt, proj_b, (void*)out, x, 65536, 256, 256);
  // adaLN2 on x1 -> buf_h (bf16)
  hipLaunchKernelGGL((adaln_kernel<1>), dim3(16384), dim3(256), 0, stream,
                     out, mod2, gamma2, beta2, buf_h);
  for (int c = 0; c < 4; ++c) {
    const bf16* hA = buf_h + (long)c * 16384 * 256;
    float* oc = out + (long)c * 16384 * 256;
    hipLaunchKernelGGL((gemm_mfma<1>), dim3(128, 8), dim3(256), 0, stream,
                       hA, fc1_wt, fc1_b, (void*)chunk, (const float*)nullptr, 16384, 1024, 256);
    hipLaunchKernelGGL((gemm_mfma<2>), dim3(128, 2), dim3(256), 0, stream,
                       chunk, fc2_wt, fc2_b, (void*)oc, oc, 16384, 256, 1024);
  }
}

// Round 6
// 463.888 us; speedup vs baseline: 4.9157x; 1.2554x over previous
//
#include <hip/hip_runtime.h>
#include <hip/hip_bf16.h>
#include <math.h>

#define SHIFT_ 4
#define NH_ 8
#define DIM_ 256
#define COND_ 128
#define HID_ 1024

typedef __hip_bfloat16 bf16;
typedef __attribute__((ext_vector_type(8))) short short8;
typedef __attribute__((ext_vector_type(4))) float f32x4;

__device__ inline unsigned pack2(float a, float b) {
  bf16 x = __float2bfloat16(a), y = __float2bfloat16(b);
  unsigned short ux = *(unsigned short*)&x, uy = *(unsigned short*)&y;
  return (unsigned)ux | ((unsigned)uy << 16);
}

#define GL_LDS16(g, l) __builtin_amdgcn_global_load_lds( \
    (const __attribute__((address_space(1))) unsigned*)(g), \
    (__attribute__((address_space(3))) unsigned*)(l), 16, 0, 0)

// ---------------- weight prep: wt[n*K+k] = bf16(w[k*N+n]) ----------------
__global__ __launch_bounds__(256) void wprep_kernel(const float* __restrict__ w,
    bf16* __restrict__ wt, int K, int N) {
  int idx = blockIdx.x * 256 + threadIdx.x;
  if (idx >= K * N) return;
  int k = idx / N, n = idx - k * N;
  wt[(long)n * K + k] = __float2bfloat16(w[idx]);
}

// ---------------- rel-pos bias in MFMA C-fragment order ----------------
// layout: [h][mi][ni][lane][r], n = 16*mi + (lane>>4)*4 + r, m = 16*ni + (lane&15)
__global__ __launch_bounds__(256) void bias_prep(const float* __restrict__ rpb,
    float* __restrict__ bfr) {
  int t = blockIdx.x * 256 + threadIdx.x;   // 0..8191
  int h = t >> 10, mi = (t >> 8) & 3, ni = (t >> 6) & 3, lane = t & 63;
  int g = lane >> 4, l15 = lane & 15;
  int m = 16 * ni + l15;
#pragma unroll
  for (int r = 0; r < 4; ++r) {
    int n = 16 * mi + g * 4 + r;
    int idx = ((n >> 3) - (m >> 3) + 7) * 15 + ((n & 7) - (m & 7) + 7);
    bfr[(((h * 4 + mi) * 4 + ni) * 64 + lane) * 4 + r] = rpb[idx * NH_ + h];
  }
}

// ---------------- mod = cond @ w + b ----------------
__global__ __launch_bounds__(256) void mod_kernel(const float* __restrict__ cond,
    const float* __restrict__ w1, const float* __restrict__ b1,
    const float* __restrict__ w2, const float* __restrict__ b2,
    float* __restrict__ mod1, float* __restrict__ mod2) {
  int gid = blockIdx.x * 256 + threadIdx.x;
  int sel = gid >> 13;
  int r   = gid & 8191;
  int b   = r >> 9;
  int c   = r & 511;
  const float* w  = sel ? w2 : w1;
  const float* bb = sel ? b2 : b1;
  const float* cp = cond + b * COND_;
  float acc = bb[c];
#pragma unroll 4
  for (int k = 0; k < COND_; ++k) acc += cp[k] * w[k * 512 + c];
  (sel ? mod2 : mod1)[b * 512 + c] = acc;
}

// ---------------- adaLN -> bf16 out (+ optional shift-window gather) ----------------
template <int MODE>
__global__ __launch_bounds__(256) void adaln_kernel(const float* __restrict__ x,
    const float* __restrict__ mod, const float* __restrict__ gamma,
    const float* __restrict__ beta, bf16* __restrict__ out) {
  int lane = threadIdx.x & 63;
  int row  = blockIdx.x * 4 + (threadIdx.x >> 6);
  int b, src;
  if (MODE == 0) {
    int w = row >> 6, n = row & 63;
    b = w >> 6;
    int wi = (w >> 3) & 7, wj = w & 7;
    int rr = (wi * 8 + (n >> 3) + SHIFT_) & 63;
    int cc = (wj * 8 + (n & 7) + SHIFT_) & 63;
    src = rr * 64 + cc;
  } else {
    b   = row >> 12;
    src = row & 4095;
  }
  float4 v = ((const float4*)(x + ((long)b * 4096 + src) * DIM_))[lane];
  float s  = v.x + v.y + v.z + v.w;
  float sq = v.x * v.x + v.y * v.y + v.z * v.z + v.w * v.w;
#pragma unroll
  for (int off = 32; off >= 1; off >>= 1) {
    s  += __shfl_xor(s, off);
    sq += __shfl_xor(sq, off);
  }
  float mean = s * (1.f / DIM_);
  float var  = sq * (1.f / DIM_) - mean * mean;
  float rstd = rsqrtf(var + 1e-6f);
  float4 g  = ((const float4*)gamma)[lane];
  float4 bt = ((const float4*)beta)[lane];
  float4 dg = ((const float4*)(mod + b * 512))[lane];
  float4 db = ((const float4*)(mod + b * 512 + 256))[lane];
  float ox = g.x * (1.f + dg.x) * ((v.x - mean) * rstd) + bt.x + db.x;
  float oy = g.y * (1.f + dg.y) * ((v.y - mean) * rstd) + bt.y + db.y;
  float oz = g.z * (1.f + dg.z) * ((v.z - mean) * rstd) + bt.z + db.z;
  float ow = g.w * (1.f + dg.w) * ((v.w - mean) * rstd) + bt.w + db.w;
  ((uint2*)(out + (long)row * DIM_))[lane] = make_uint2(pack2(ox, oy), pack2(oz, ow));
}

// ---------------- MFMA GEMM v2: 256x128 tile, 512 thr, double-buffered stage-early ----
// out[M,N] = A_bf16[M,K] @ Wt_bf16[N,K]^T + bias
// EPI 0: bias, bf16 out | 1: bias+GELU, bf16 out | 2: bias+res, f32 out
// EPI 3: proj scatter + res, f32 out | 4: bias, bf16 out, cols<256 scaled by 1/sqrt(32)
template <int EPI>
__global__ __launch_bounds__(512) void gemm_mfma2(const bf16* __restrict__ A,
    const bf16* __restrict__ Wt, const float* __restrict__ bias,
    void* __restrict__ outv, const float* __restrict__ res,
    int M, int N, int K) {
  __shared__ __align__(16) bf16 As[2][256 * 32];
  __shared__ __align__(16) bf16 Bs[2][128 * 32];
  int tid = threadIdx.x;                  // 0..511
  int bm = blockIdx.x * 256, bn = blockIdx.y * 128;
  int lane = tid & 63, wid = tid >> 6;    // 8 waves
  int wm = (wid >> 1) * 64, wn = (wid & 1) * 64;
  int l15 = lane & 15, kg = (lane >> 4) * 8;

  f32x4 acc[4][4];
#pragma unroll
  for (int i = 0; i < 4; ++i)
#pragma unroll
    for (int j = 0; j < 4; ++j) acc[i][j] = (f32x4){0.f, 0.f, 0.f, 0.f};

  // staging map: 16 B per thread per load; A buffer 16 KB (2 rounds), B 8 KB (1 round)
  int oa1 = tid * 16;              // bytes [0, 8192)
  int oa2 = oa1 + 8192;            // bytes [8192, 16384)
  int rowa1 = oa1 >> 6, ca1 = oa1 & 63;   // 64 B per 32-elem bf16 row
  int rowa2 = rowa1 + 128;

  auto stage = [&](int bi, int kk) {
    GL_LDS16((const char*)A  + ((long)(bm + rowa1) * K + kk) * 2 + ca1, (char*)(&As[bi][0]) + oa1);
    GL_LDS16((const char*)A  + ((long)(bm + rowa2) * K + kk) * 2 + ca1, (char*)(&As[bi][0]) + oa2);
    GL_LDS16((const char*)Wt + ((long)(bn + rowa1) * K + kk) * 2 + ca1, (char*)(&Bs[bi][0]) + oa1);
  };

  stage(0, 0);
  __syncthreads();
  int nt = K >> 5;
  for (int t = 0; t < nt; ++t) {
    int cur = t & 1;
    if (t + 1 < nt) stage(cur ^ 1, (t + 1) << 5);   // issue next tile early
    short8 af[4], bfr[4];
#pragma unroll
    for (int mi = 0; mi < 4; ++mi)
      af[mi] = *(const short8*)(&As[cur][0] + (wm + mi * 16 + l15) * 32 + kg);
#pragma unroll
    for (int ni = 0; ni < 4; ++ni)
      bfr[ni] = *(const short8*)(&Bs[cur][0] + (wn + ni * 16 + l15) * 32 + kg);
#pragma unroll
    for (int mi = 0; mi < 4; ++mi)
#pragma unroll
      for (int ni = 0; ni < 4; ++ni)
        acc[mi][ni] = __builtin_amdgcn_mfma_f32_16x16x32_bf16(af[mi], bfr[ni], acc[mi][ni], 0, 0, 0);
    if (t + 1 < nt) __syncthreads();   // single barrier/step: drains next-tile DMA + our reads
  }

  int col0 = bn + wn + l15;
  int r0 = (lane >> 4) * 4;
#pragma unroll
  for (int mi = 0; mi < 4; ++mi) {
#pragma unroll
    for (int r = 0; r < 4; ++r) {
      int row = bm + wm + mi * 16 + r0 + r;
      long dst = row;
      if (EPI == 3) {
        int w = row >> 6, n = row & 63;
        int b = w >> 6, wi = (w >> 3) & 7, wj = w & 7;
        int rr = (wi * 8 + (n >> 3) + SHIFT_) & 63;
        int cc = (wj * 8 + (n & 7) + SHIFT_) & 63;
        dst = (long)b * 4096 + rr * 64 + cc;
      }
#pragma unroll
      for (int ni = 0; ni < 4; ++ni) {
        int col = col0 + ni * 16;
        float v = acc[mi][ni][r] + bias[col];
        if (EPI == 1) v = 0.5f * v * (1.f + erff(v * 0.70710678118654752f));
        if (EPI == 4 && col < 256) v *= 0.17677669529663689f;
        if (EPI <= 1 || EPI == 4) {
          ((bf16*)outv)[(long)row * N + col] = __float2bfloat16(v);
        } else if (EPI == 2) {
          ((float*)outv)[(long)row * N + col] = v + res[(long)row * N + col];
        } else {
          ((float*)outv)[dst * DIM_ + col] = v + res[dst * DIM_ + col];
        }
      }
    }
  }
}

// ---------------- MFMA attention: block = 1 window, 4 waves, 2 heads/wave ------------
__global__ __launch_bounds__(256) void attn_mfma(const bf16* __restrict__ qkv,
    const float* __restrict__ bias_frag, bf16* __restrict__ o) {
  __shared__ __align__(16) bf16 Pl[4][64 * 72];
  __shared__ __align__(16) bf16 Vtl[4][32 * 72];
  int tid = threadIdx.x;
  int wave = tid >> 6, lane = tid & 63;
  int l15 = lane & 15, g = lane >> 4;
  int wl = blockIdx.x;
  bf16* P  = Pl[wave];
  bf16* VT = Vtl[wave];

#pragma unroll
  for (int hh = 0; hh < 2; ++hh) {
    int h = wave + hh * 4;
    const bf16* base = qkv + (long)wl * 64 * 768 + h * 32;

    __syncthreads();  // protect VT/P vs previous iteration's reads

    // ---- stage V^T: VT[d][m] from V[m][d] ----
#pragma unroll
    for (int t = 0; t < 4; ++t) {
      int m  = t * 16 + (lane >> 2);
      int d0 = (lane & 3) * 8;
      short8 v = *(const short8*)(base + (long)m * 768 + 512 + d0);
#pragma unroll
      for (int j = 0; j < 8; ++j) VT[(d0 + j) * 72 + m] = ((const bf16*)&v)[j];
    }

    // ---- Q/K fragments direct from global ----
    short8 aq[4], bk[4];
#pragma unroll
    for (int mi = 0; mi < 4; ++mi)
      aq[mi] = *(const short8*)(base + (long)(l15 + 16 * mi) * 768 + g * 8);
#pragma unroll
    for (int ni = 0; ni < 4; ++ni)
      bk[ni] = *(const short8*)(base + (long)(l15 + 16 * ni) * 768 + 256 + g * 8);

    // ---- S = Q@K^T + bias (acc init = bias fragment) ----
    f32x4 s[4][4];
#pragma unroll
    for (int mi = 0; mi < 4; ++mi)
#pragma unroll
      for (int ni = 0; ni < 4; ++ni)
        s[mi][ni] = *(const f32x4*)(bias_frag + (((h * 4 + mi) * 4 + ni) * 64 + lane) * 4);
#pragma unroll
    for (int mi = 0; mi < 4; ++mi)
#pragma unroll
      for (int ni = 0; ni < 4; ++ni)
        s[mi][ni] = __builtin_amdgcn_mfma_f32_16x16x32_bf16(aq[mi], bk[ni], s[mi][ni], 0, 0, 0);

    // ---- in-register softmax over m ----
    float inv[4][4];
#pragma unroll
    for (int mi = 0; mi < 4; ++mi) {
#pragma unroll
      for (int r = 0; r < 4; ++r) {
        float mx = fmaxf(fmaxf(s[mi][0][r], s[mi][1][r]), fmaxf(s[mi][2][r], s[mi][3][r]));
        mx = fmaxf(mx, __shfl_xor(mx, 1));
        mx = fmaxf(mx, __shfl_xor(mx, 2));
        mx = fmaxf(mx, __shfl_xor(mx, 4));
        mx = fmaxf(mx, __shfl_xor(mx, 8));
        float e0 = __expf(s[mi][0][r] - mx);
        float e1 = __expf(s[mi][1][r] - mx);
        float e2 = __expf(s[mi][2][r] - mx);
        float e3 = __expf(s[mi][3][r] - mx);
        int n = 16 * mi + g * 4 + r;
        P[n * 72 + l15 +  0] = __float2bfloat16(e0);
        P[n * 72 + l15 + 16] = __float2bfloat16(e1);
        P[n * 72 + l15 + 32] = __float2bfloat16(e2);
        P[n * 72 + l15 + 48] = __float2bfloat16(e3);
        float sm = (e0 + e1) + (e2 + e3);
        sm += __shfl_xor(sm, 1);
        sm += __shfl_xor(sm, 2);
        sm += __shfl_xor(sm, 4);
        sm += __shfl_xor(sm, 8);
        inv[mi][r] = 1.f / sm;
      }
    }

    __syncthreads();

    // ---- O = P @ V^T ----
    f32x4 ov[4][2];
#pragma unroll
    for (int mi = 0; mi < 4; ++mi)
#pragma unroll
      for (int ni = 0; ni < 2; ++ni) ov[mi][ni] = (f32x4){0.f, 0.f, 0.f, 0.f};
#pragma unroll
    for (int kt = 0; kt < 2; ++kt) {
      short8 ap[4], bv[2];
#pragma unroll
      for (int mi = 0; mi < 4; ++mi)
        ap[mi] = *(const short8*)(P + (l15 + 16 * mi) * 72 + kt * 32 + g * 8);
#pragma unroll
      for (int ni = 0; ni < 2; ++ni)
        bv[ni] = *(const short8*)(VT + (l15 + 16 * ni) * 72 + kt * 32 + g * 8);
#pragma unroll
      for (int mi = 0; mi < 4; ++mi)
#pragma unroll
        for (int ni = 0; ni < 2; ++ni)
          ov[mi][ni] = __builtin_amdgcn_mfma_f32_16x16x32_bf16(ap[mi], bv[ni], ov[mi][ni], 0, 0, 0);
    }

#pragma unroll
    for (int mi = 0; mi < 4; ++mi)
#pragma unroll
      for (int ni = 0; ni < 2; ++ni)
#pragma unroll
        for (int r = 0; r < 4; ++r) {
          int n = 16 * mi + g * 4 + r;
          int d = l15 + 16 * ni;
          o[(long)(wl * 64 + n) * DIM_ + h * 32 + d] =
              __float2bfloat16(ov[mi][ni][r] * inv[mi][r]);
        }
  }
}

extern "C" void kernel_launch(void* const* d_in, const int* in_sizes, int n_in,
                              void* d_out, int out_size, void* d_ws, size_t ws_size,
                              hipStream_t stream) {
  const float* x      = (const float*)d_in[0];
  const float* cond   = (const float*)d_in[1];
  const float* gamma1 = (const float*)d_in[4];
  const float* beta1  = (const float*)d_in[5];
  const float* mod1_w = (const float*)d_in[6];
  const float* mod1_b = (const float*)d_in[7];
  const float* qkv_w  = (const float*)d_in[8];
  const float* qkv_b  = (const float*)d_in[9];
  const float* rpb    = (const float*)d_in[10];
  const float* proj_w = (const float*)d_in[11];
  const float* proj_b = (const float*)d_in[12];
  const float* gamma2 = (const float*)d_in[13];
  const float* beta2  = (const float*)d_in[14];
  const float* mod2_w = (const float*)d_in[15];
  const float* mod2_b = (const float*)d_in[16];
  const float* fc1_w  = (const float*)d_in[17];
  const float* fc1_b  = (const float*)d_in[18];
  const float* fc2_w  = (const float*)d_in[19];
  const float* fc2_b  = (const float*)d_in[20];
  float* out = (float*)d_out;

  // workspace layout (~170 MB):
  //   mod1/mod2 64 KB | weights ~1.6 MB | bias_frag 128 KB
  //   buf_h: 65536*256 bf16 (33.5 MB) | big: 65536*1024 bf16 (134 MB; qkv then hid)
  char* wsb     = (char*)d_ws;
  float* mod1   = (float*)wsb;
  float* mod2   = mod1 + 8192;
  bf16* qkv_wt  = (bf16*)(wsb + 65536);
  bf16* proj_wt = qkv_wt + 256 * 768;
  bf16* fc1_wt  = proj_wt + 256 * 256;
  bf16* fc2_wt  = fc1_wt + 256 * 1024;
  float* bias_frag = (float*)(fc2_wt + 1024 * 256);   // 32768 f32
  bf16* buf_h   = (bf16*)(bias_frag + 32768);
  bf16* big     = buf_h + (long)65536 * 256;

  hipLaunchKernelGGL(wprep_kernel, dim3(768), dim3(256), 0, stream, qkv_w, qkv_wt, 256, 768);
  hipLaunchKernelGGL(wprep_kernel, dim3(256), dim3(256), 0, stream, proj_w, proj_wt, 256, 256);
  hipLaunchKernelGGL(wprep_kernel, dim3(1024), dim3(256), 0, stream, fc1_w, fc1_wt, 256, 1024);
  hipLaunchKernelGGL(wprep_kernel, dim3(1024), dim3(256), 0, stream, fc2_w, fc2_wt, 1024, 256);
  hipLaunchKernelGGL(bias_prep, dim3(32), dim3(256), 0, stream, rpb, bias_frag);

  hipLaunchKernelGGL(mod_kernel, dim3(64), dim3(256), 0, stream,
                     cond, mod1_w, mod1_b, mod2_w, mod2_b, mod1, mod2);
  hipLaunchKernelGGL((adaln_kernel<0>), dim3(16384), dim3(256), 0, stream,
                     x, mod1, gamma1, beta1, buf_h);
  // qkv (scaled q) -> big
  hipLaunchKernelGGL((gemm_mfma2<4>), dim3(256, 6), dim3(512), 0, stream,
                     buf_h, qkv_wt, qkv_b, (void*)big, (const float*)nullptr, 65536, 768, 256);
  // attention -> buf_h
  hipLaunchKernelGGL(attn_mfma, dim3(1024), dim3(256), 0, stream,
                     big, bias_frag, buf_h);
  // proj + window-reverse + roll + residual(x) -> d_out (= x1, f32)
  hipLaunchKernelGGL((gemm_mfma2<3>), dim3(256, 2), dim3(512), 0, stream,
                     buf_h, proj_wt, proj_b, (void*)out, x, 65536, 256, 256);
  // adaLN2 on x1 -> buf_h (bf16)
  hipLaunchKernelGGL((adaln_kernel<1>), dim3(16384), dim3(256), 0, stream,
                     out, mod2, gamma2, beta2, buf_h);
  // fc1 + GELU -> big
  hipLaunchKernelGGL((gemm_mfma2<1>), dim3(256, 8), dim3(512), 0, stream,
                     buf_h, fc1_wt, fc1_b, (void*)big, (const float*)nullptr, 65536, 1024, 256);
  // fc2 + residual(x1 in d_out) -> d_out
  hipLaunchKernelGGL((gemm_mfma2<2>), dim3(256, 2), dim3(512), 0, stream,
                     big, fc2_wt, fc2_b, (void*)out, out, 65536, 256, 1024);
}